// Round 13
// baseline (60.989 us; speedup 1.0000x reference)
//
#include <hip/hip_runtime.h>
#include <hip/hip_bf16.h>

#define B_ 32
#define L_ 2048
#define E_ 256
#define H_ 256
#define MAXSTEP 20
#define NL 2       // l's per block
#define NCH2 52    // ceil(103/NL)
#define NGRP2 (MAXSTEP * NCH2)   // 1040 blocks x 4 waves

typedef __attribute__((ext_vector_type(4))) float f32x4;
typedef __attribute__((ext_vector_type(8))) short bf16x8;
using bf16 = __hip_bfloat16;

__device__ inline short cvt1(float x) {
    bf16 b = __float2bfloat16(x);
    return *reinterpret_cast<short*>(&b);
}

// ---------- Pass 1a: elementwise fp32 -> bf16 (same [b][l][e] layout). ----------
__global__ __launch_bounds__(256) void convert_a_kernel(
        const float* __restrict__ A, short* __restrict__ Abf, int n8) {
    // n8 = number of 8-element groups (16.78M/8). Grid-stride.
    for (int i = blockIdx.x * blockDim.x + threadIdx.x; i < n8; i += gridDim.x * blockDim.x) {
        const float* p = A + (size_t)i * 8;
        f32x4 lo = *(const f32x4*)p;
        f32x4 hi = *(const f32x4*)(p + 4);
        bf16x8 v;
#pragma unroll
        for (int j = 0; j < 4; ++j) {
            v[j]     = cvt1(lo[j]);
            v[j + 4] = cvt1(hi[j]);
        }
        *(bf16x8*)(Abf + (size_t)i * 8) = v;
    }
}

// ---------- Pass 1b: transpose + convert cnn fp32 [s][e][h] -> wt bf16 [s][h][e]. ----------
__global__ void transpose_w_kernel(const float* __restrict__ cnn, short* __restrict__ wt) {
    __shared__ short tile[32][33];
    const int s  = blockIdx.z;
    const int e0 = blockIdx.y * 32;
    const int h0 = blockIdx.x * 32;
    const int tx = threadIdx.x;
    const int ty = threadIdx.y;
    const float* src = cnn + ((size_t)s * E_ + e0) * H_ + h0;
#pragma unroll
    for (int i = ty; i < 32; i += 8)
        tile[i][tx] = cvt1(src[(size_t)i * H_ + tx]);
    __syncthreads();
    short* dst = wt + ((size_t)s * H_ + h0) * E_ + e0;
#pragma unroll
    for (int i = ty; i < 32; i += 8)
        dst[(size_t)i * E_ + tx] = tile[tx][i];
}

// ---------- Pass 2: bf16 MFMA kernel, kk-grouped LDS, conflict-free. ----------
// Block = (s, chunk), 4 waves; wave wv owns cols [wv*64, wv*64+64) for NL
// same-s l's. breg (W^T[s] bf16) in 128 VGPRs, loaded FIRST (oldest in vmcnt
// queue). A-tile per l: 32 rows x 256 bf16 = 16 KB, double-buffered.
//
// LDS layout (per tile): slot(kk, b, g) at byte (kk*32 + b)*64 + g*16, i.e.
// [kk][b][g] with 16-B granules. Staged by 16 global_load_lds (1 KB each):
// instr idx = kk*2+half covers b in [half*16, half*16+16); lane = rl*4+g maps
// to global Abf[b=half*16+rl][l][kk*32+g*8] (per-lane source addressing), LDS
// dest = tile + idx*1024 + lane*16 (linear, as required).
// Compute read a0 (b=r): byte kk*2048 + r*64 + g*16 -> lanes (r=lane&15,
// g=lane>>4) hit 64 CONSECUTIVE 16-B slots => conflict-free ds_read_b128.
// a1 (b=r+16): +1024 B. NO cvt anywhere in the k-loop.
//
// Swapped-operand mfma (R12): D = mfma(breg[kk][nf], a_frag) -> lane holds 4
// consecutive h for one b -> 16-B dwordx4 stores, 8/wave/l.
// Per-wave vmcnt queue (breg=32, stage=4/tile/wave, stores=8/l):
//   it0: [breg:32|s0:4|s1:4] -> retire breg+s0 -> vmcnt(4)
//   it1: [s1:4|st0:8]        -> retire s1      -> vmcnt(8)
__global__ __launch_bounds__(256, 2) void vaw_bf16_kernel(
        const short* __restrict__ Abf, const short* __restrict__ Wt,
        float* __restrict__ out) {
    __shared__ __align__(16) short aLds[2][8192];   // 2 x 16 KB

    const int g_    = blockIdx.x;
    const int s     = g_ / NCH2;
    const int chunk = g_ % NCH2;
    const int cnt   = (s < 8) ? 103 : 102;   // #{l < 2048 : l % 20 == s}
    const int wv    = threadIdx.x >> 6;
    const int lane  = threadIdx.x & 63;
    const int r     = lane & 15;
    const int g     = lane >> 4;
    const int nbase = wv * 64;

    // ---- breg first (oldest vmcnt entries): 32 x 16B loads, L2/L3-resident.
    const short* wtb = Wt + ((size_t)s * H_ + nbase + r) * E_ + g * 8;
    bf16x8 breg[8][4];
#pragma unroll
    for (int kk = 0; kk < 8; ++kk)
#pragma unroll
        for (int nf = 0; nf < 4; ++nf)
            breg[kk][nf] = *(const bf16x8*)(wtb + (size_t)nf * 16 * E_ + kk * 32);
    __builtin_amdgcn_sched_barrier(0);

    auto lof = [&](int il) {
        int idx = chunk * NL + il;
        if (idx > cnt - 1) idx = cnt - 1;    // tail clamp: duplicate work, benign
        return s + 20 * idx;
    };

    // Stage tile for iter it into aLds[it&1]: wave wv issues instrs
    // idx = wv*4 + j (j=0..3); kk = idx>>1, half = idx&1.
    const int rl = lane >> 2;                // 0..15
    const int gc = lane & 3;                 // 0..3
    auto stage = [&](int it) {
        const int l = lof(it);
        short* dst = aLds[it & 1];
#pragma unroll
        for (int j = 0; j < 4; ++j) {
            const int idx  = wv * 4 + j;
            const int kk   = idx >> 1;
            const int half = idx & 1;
            const int b    = half * 16 + rl;
            const short* gp = Abf + ((size_t)b * L_ + l) * E_ + kk * 32 + gc * 8;
            __builtin_amdgcn_global_load_lds(
                (const __attribute__((address_space(1))) void*)gp,
                (__attribute__((address_space(3))) void*)&dst[idx * 512],
                16, 0, 0);
        }
    };

    stage(0);
    stage(1);
    __builtin_amdgcn_sched_barrier(0);

#pragma unroll
    for (int it = 0; it < NL; ++it) {
        const int l   = lof(it);
        const int cur = it & 1;

        if (it == 0) asm volatile("s_waitcnt vmcnt(4)" ::: "memory");
        else         asm volatile("s_waitcnt vmcnt(8)" ::: "memory");
        __builtin_amdgcn_s_barrier();        // all waves' stage(it) landed
        __builtin_amdgcn_sched_barrier(0);

        // acc[nf][hf]: nf = h-frag, hf = b-half (0: b=r, 1: b=r+16)
        f32x4 acc[4][2];
#pragma unroll
        for (int nf = 0; nf < 4; ++nf)
#pragma unroll
            for (int hf = 0; hf < 2; ++hf)
                acc[nf][hf] = f32x4{0.f, 0.f, 0.f, 0.f};

#pragma unroll
        for (int kk = 0; kk < 8; ++kk) {
            // conflict-free: 64 consecutive 16-B slots per read
            bf16x8 a0 = *(const bf16x8*)&aLds[cur][kk * 1024 + (r * 4 + g) * 8];
            bf16x8 a1 = *(const bf16x8*)&aLds[cur][kk * 1024 + 512 + (r * 4 + g) * 8];
#pragma unroll
            for (int nf = 0; nf < 4; ++nf) {
                acc[nf][0] = __builtin_amdgcn_mfma_f32_16x16x32_bf16(breg[kk][nf], a0, acc[nf][0], 0, 0, 0);
                acc[nf][1] = __builtin_amdgcn_mfma_f32_16x16x32_bf16(breg[kk][nf], a1, acc[nf][1], 0, 0, 0);
            }
        }

        // Coalesced epilogue: one dwordx4 per (hf, nf) = 8 stores.
#pragma unroll
        for (int hf = 0; hf < 2; ++hf) {
            const int b = r + 16 * hf;
            float* orow = out + ((size_t)b * L_ + l) * H_ + nbase + g * 4;
#pragma unroll
            for (int nf = 0; nf < 4; ++nf)
                *(f32x4*)(orow + nf * 16) = acc[nf][hf];
        }
        if (l == L_ - 1) {
            float* out2 = out + (size_t)B_ * L_ * H_;
#pragma unroll
            for (int hf = 0; hf < 2; ++hf) {
                const int b = r + 16 * hf;
                float* orow = out2 + (size_t)b * H_ + nbase + g * 4;
#pragma unroll
                for (int nf = 0; nf < 4; ++nf)
                    *(f32x4*)(orow + nf * 16) = acc[nf][hf];
            }
        }

        __builtin_amdgcn_s_barrier();   // reads of buf[cur] done before overwrite
    }
}

// ---------- Fallback A (ws fits Wt only): R12 fp32-staging kernel. ----------
#define NCH 26
#define NGRP (MAXSTEP * NCH)
__global__ __launch_bounds__(256, 2) void vaw_swap_kernel(
        const float* __restrict__ A, const short* __restrict__ Wt,
        float* __restrict__ out) {
    __shared__ __align__(16) float aLds[2][B_ * E_];
    const int g_    = blockIdx.x;
    const int s     = g_ / NCH;
    const int chunk = g_ % NCH;
    const int cnt   = (s < 8) ? 103 : 102;
    const int wv    = threadIdx.x >> 6;
    const int lane  = threadIdx.x & 63;
    const int r     = lane & 15;
    const int g     = lane >> 4;
    const int nbase = wv * 64;
    const int key   = r & 7;

    const short* wtb = Wt + ((size_t)s * H_ + nbase + r) * E_ + g * 8;
    bf16x8 breg[8][4];
#pragma unroll
    for (int kk = 0; kk < 8; ++kk)
#pragma unroll
        for (int nf = 0; nf < 4; ++nf)
            breg[kk][nf] = *(const bf16x8*)(wtb + (size_t)nf * 16 * E_ + kk * 32);

    auto lof = [&](int il) {
        int idx = chunk * 4 + il;
        if (idx > cnt - 1) idx = cnt - 1;
        return s + 20 * idx;
    };
    auto stage = [&](int it) {
        const int l = lof(it);
        float* dst = aLds[it & 1];
#pragma unroll
        for (int t = 0; t < 8; ++t) {
            const int b  = t * 4 + wv;
            const int cg = lane ^ (b & 7);
            const float* gp = A + ((size_t)b * L_ + l) * E_ + cg * 4;
            __builtin_amdgcn_global_load_lds(
                (const __attribute__((address_space(1))) void*)gp,
                (__attribute__((address_space(3))) void*)&dst[b * 256],
                16, 0, 0);
        }
    };

    stage(0);
#pragma unroll 1
    for (int it = 0; it < 4; ++it) {
        const int l   = lof(it);
        const int cur = it & 1;
        if (it < 3) stage(it + 1);
        if (it == 0)      asm volatile("s_waitcnt vmcnt(8)"  ::: "memory");
        else if (it < 3)  asm volatile("s_waitcnt vmcnt(16)" ::: "memory");
        else              asm volatile("s_waitcnt vmcnt(8)"  ::: "memory");
        __builtin_amdgcn_s_barrier();
        __builtin_amdgcn_sched_barrier(0);

        f32x4 acc[4][2];
#pragma unroll
        for (int nf = 0; nf < 4; ++nf)
#pragma unroll
            for (int hf = 0; hf < 2; ++hf)
                acc[nf][hf] = f32x4{0.f, 0.f, 0.f, 0.f};

#pragma unroll
        for (int kk = 0; kk < 8; ++kk) {
            const int c0 = kk * 8 + g * 2;
            f32x4 a0lo = *(const f32x4*)&aLds[cur][r * 256 + ((c0 ^ key) << 2)];
            f32x4 a0hi = *(const f32x4*)&aLds[cur][r * 256 + (((c0 + 1) ^ key) << 2)];
            f32x4 a1lo = *(const f32x4*)&aLds[cur][(r + 16) * 256 + ((c0 ^ key) << 2)];
            f32x4 a1hi = *(const f32x4*)&aLds[cur][(r + 16) * 256 + (((c0 + 1) ^ key) << 2)];
            bf16x8 a0, a1;
#pragma unroll
            for (int j = 0; j < 4; ++j) {
                a0[j]     = cvt1(a0lo[j]);
                a0[j + 4] = cvt1(a0hi[j]);
                a1[j]     = cvt1(a1lo[j]);
                a1[j + 4] = cvt1(a1hi[j]);
            }
#pragma unroll
            for (int nf = 0; nf < 4; ++nf) {
                acc[nf][0] = __builtin_amdgcn_mfma_f32_16x16x32_bf16(breg[kk][nf], a0, acc[nf][0], 0, 0, 0);
                acc[nf][1] = __builtin_amdgcn_mfma_f32_16x16x32_bf16(breg[kk][nf], a1, acc[nf][1], 0, 0, 0);
            }
        }

#pragma unroll
        for (int hf = 0; hf < 2; ++hf) {
            const int b = r + 16 * hf;
            float* orow = out + ((size_t)b * L_ + l) * H_ + nbase + g * 4;
#pragma unroll
            for (int nf = 0; nf < 4; ++nf)
                *(f32x4*)(orow + nf * 16) = acc[nf][hf];
        }
        if (l == L_ - 1) {
            float* out2 = out + (size_t)B_ * L_ * H_;
#pragma unroll
            for (int hf = 0; hf < 2; ++hf) {
                const int b = r + 16 * hf;
                float* orow = out2 + (size_t)b * H_ + nbase + g * 4;
#pragma unroll
                for (int nf = 0; nf < 4; ++nf)
                    *(f32x4*)(orow + nf * 16) = acc[nf][hf];
            }
        }
        __builtin_amdgcn_s_barrier();
    }
}

// ---------- Fallback B (no workspace): fp32 B loads per k-step. ----------
__global__ __launch_bounds__(256) void vaw_fallback_kernel(
        const float* __restrict__ A, const float* __restrict__ W, float* __restrict__ out) {
    __shared__ __align__(16) float aLds[2][B_ * E_];
    const int l0   = blockIdx.x * 4;
    const int wv   = threadIdx.x >> 6;
    const int lane = threadIdx.x & 63;
    const int r    = lane & 15;
    const int g    = lane >> 4;
    const int nbase = wv * 64;
    const int key   = r & 7;

    auto stage = [&](int it) {
        float* dst = aLds[it & 1];
        const int l = l0 + it;
#pragma unroll
        for (int t = 0; t < 8; ++t) {
            const int b  = t * 4 + wv;
            const int cgx = lane ^ (b & 7);
            const float* gp = A + ((size_t)b * L_ + l) * E_ + cgx * 4;
            __builtin_amdgcn_global_load_lds(
                (const __attribute__((address_space(1))) void*)gp,
                (__attribute__((address_space(3))) void*)&dst[b * 256],
                16, 0, 0);
        }
    };

    stage(0);
#pragma unroll 1
    for (int it = 0; it < 4; ++it) {
        const int l   = l0 + it;
        const int sidx = l % MAXSTEP;
        const int cur = it & 1;
        if (it < 3) {
            stage(it + 1);
            asm volatile("s_waitcnt vmcnt(8)" ::: "memory");
        } else {
            asm volatile("s_waitcnt vmcnt(0)" ::: "memory");
        }
        __builtin_amdgcn_s_barrier();
        __builtin_amdgcn_sched_barrier(0);

        f32x4 acc[2][4] = {};
        const float* Wf = W + (size_t)sidx * E_ * H_;
#pragma unroll 2
        for (int kk = 0; kk < 8; ++kk) {
            const int k0 = kk * 32;
            const int c0 = kk * 8 + g * 2;
            f32x4 a0lo = *(const f32x4*)&aLds[cur][r * 256 + ((c0 ^ key) << 2)];
            f32x4 a0hi = *(const f32x4*)&aLds[cur][r * 256 + (((c0 + 1) ^ key) << 2)];
            f32x4 a1lo = *(const f32x4*)&aLds[cur][(r + 16) * 256 + ((c0 ^ key) << 2)];
            f32x4 a1hi = *(const f32x4*)&aLds[cur][(r + 16) * 256 + (((c0 + 1) ^ key) << 2)];
            bf16x8 a0, a1;
#pragma unroll
            for (int j = 0; j < 4; ++j) {
                a0[j]     = cvt1(a0lo[j]);
                a0[j + 4] = cvt1(a0hi[j]);
                a1[j]     = cvt1(a1lo[j]);
                a1[j + 4] = cvt1(a1hi[j]);
            }
            bf16x8 b0, b1, b2, b3;
#pragma unroll
            for (int j = 0; j < 8; ++j) {
                const size_t krow = (size_t)(k0 + g * 8 + j) * H_;
                b0[j] = cvt1(Wf[krow + nbase +  0 + r]);
                b1[j] = cvt1(Wf[krow + nbase + 16 + r]);
                b2[j] = cvt1(Wf[krow + nbase + 32 + r]);
                b3[j] = cvt1(Wf[krow + nbase + 48 + r]);
            }
            acc[0][0] = __builtin_amdgcn_mfma_f32_16x16x32_bf16(a0, b0, acc[0][0], 0, 0, 0);
            acc[0][1] = __builtin_amdgcn_mfma_f32_16x16x32_bf16(a0, b1, acc[0][1], 0, 0, 0);
            acc[0][2] = __builtin_amdgcn_mfma_f32_16x16x32_bf16(a0, b2, acc[0][2], 0, 0, 0);
            acc[0][3] = __builtin_amdgcn_mfma_f32_16x16x32_bf16(a0, b3, acc[0][3], 0, 0, 0);
            acc[1][0] = __builtin_amdgcn_mfma_f32_16x16x32_bf16(a1, b0, acc[1][0], 0, 0, 0);
            acc[1][1] = __builtin_amdgcn_mfma_f32_16x16x32_bf16(a1, b1, acc[1][1], 0, 0, 0);
            acc[1][2] = __builtin_amdgcn_mfma_f32_16x16x32_bf16(a1, b2, acc[1][2], 0, 0, 0);
            acc[1][3] = __builtin_amdgcn_mfma_f32_16x16x32_bf16(a1, b3, acc[1][3], 0, 0, 0);
        }

        const int row0 = g * 4;
#pragma unroll
        for (int mf = 0; mf < 2; ++mf)
#pragma unroll
            for (int nf = 0; nf < 4; ++nf) {
                const int h = nbase + nf * 16 + r;
#pragma unroll
                for (int i = 0; i < 4; ++i) {
                    const int bb = mf * 16 + row0 + i;
                    out[((size_t)bb * L_ + l) * H_ + h] = acc[mf][nf][i];
                }
            }
        if (l == L_ - 1) {
            float* out2 = out + (size_t)B_ * L_ * H_;
#pragma unroll
            for (int mf = 0; mf < 2; ++mf)
#pragma unroll
                for (int nf = 0; nf < 4; ++nf) {
                    const int h = nbase + nf * 16 + r;
#pragma unroll
                    for (int i = 0; i < 4; ++i) {
                        const int bb = mf * 16 + row0 + i;
                        out2[(size_t)bb * H_ + h] = acc[mf][nf][i];
                    }
                }
        }
        __builtin_amdgcn_s_barrier();
    }
}

extern "C" void kernel_launch(void* const* d_in, const int* in_sizes, int n_in,
                              void* d_out, int out_size, void* d_ws, size_t ws_size,
                              hipStream_t stream) {
    const float* word_rep = (const float*)d_in[0];
    const float* cnn      = (const float*)d_in[1];
    float* out = (float*)d_out;

    const size_t wt_bytes  = (size_t)MAXSTEP * E_ * H_ * sizeof(short);   // 2.62 MB
    const size_t abf_bytes = (size_t)B_ * L_ * E_ * sizeof(short);        // 33.55 MB

    if (ws_size >= wt_bytes + abf_bytes) {
        short* wt  = (short*)d_ws;
        short* abf = (short*)((char*)d_ws + wt_bytes);
        transpose_w_kernel<<<dim3(8, 8, 20), dim3(32, 8), 0, stream>>>(cnn, wt);
        const int n8 = B_ * L_ * E_ / 8;
        convert_a_kernel<<<dim3(2048), dim3(256), 0, stream>>>(word_rep, abf, n8);
        vaw_bf16_kernel<<<dim3(NGRP2), dim3(256), 0, stream>>>(abf, wt, out);
    } else if (ws_size >= wt_bytes) {
        short* wt = (short*)d_ws;
        transpose_w_kernel<<<dim3(8, 8, 20), dim3(32, 8), 0, stream>>>(cnn, wt);
        vaw_swap_kernel<<<dim3(NGRP), dim3(256), 0, stream>>>(word_rep, wt, out);
    } else {
        vaw_fallback_kernel<<<dim3(L_ / 4), dim3(256), 0, stream>>>(word_rep, cnn, out);
    }
}

// Round 14
// 57.835 us; speedup vs baseline: 1.0545x; 1.0545x over previous
//
#include <hip/hip_runtime.h>
#include <hip/hip_bf16.h>

#define B_ 32
#define L_ 2048
#define E_ 256
#define H_ 256
#define MAXSTEP 20

typedef __attribute__((ext_vector_type(4))) float f32x4;
typedef __attribute__((ext_vector_type(8))) short bf16x8;
using bf16 = __hip_bfloat16;

__device__ inline short cvt1(float x) {
    bf16 b = __float2bfloat16(x);
    return *reinterpret_cast<short*>(&b);
}

// Transpose + convert: cnn fp32 [s][e][h] -> wt bf16 [s][h][e] (K-contiguous).
__global__ void transpose_w_kernel(const float* __restrict__ cnn, short* __restrict__ wt) {
    __shared__ short tile[32][33];
    const int s  = blockIdx.z;
    const int e0 = blockIdx.y * 32;
    const int h0 = blockIdx.x * 32;
    const int tx = threadIdx.x;
    const int ty = threadIdx.y;
    const float* src = cnn + ((size_t)s * E_ + e0) * H_ + h0;
#pragma unroll
    for (int i = ty; i < 32; i += 8)
        tile[i][tx] = cvt1(src[(size_t)i * H_ + tx]);
    __syncthreads();
    short* dst = wt + ((size_t)s * H_ + h0) * E_ + e0;
#pragma unroll
    for (int i = ty; i < 32; i += 8)
        dst[(size_t)i * E_ + tx] = tile[tx][i];
}

// Concurrency-first single-shot blocks: grid = 2048, block = one position l.
// NO double-buffering, NO multi-l loop — per-block critical path is minimal
// (one stage burst + one compute phase); latency hiding comes from 4-5
// resident blocks/CU (32 KB LDS, ~116 VGPR) overlapping each other.
//
// Per-wave vmem queue: [stage:8 | breg:32] -> s_waitcnt vmcnt(32) retires the
// stage; breg completion is enforced by the compiler's own waitcnt before the
// first MFMA use. ONE barrier (LDS-ready); none after (block exits).
//
// A staged fp32 (32 rows x 1 KB) via global_load_lds; source XOR-swizzled per
// 16B chunk (chunk c of row b from global chunk c^(b&7)); LDS dest linear
// (hardware requirement); compute reads apply the same XOR -> 2-way bank
// aliasing only (free, m136).
// Swapped-operand MFMA (verified R12): D = mfma(breg[kk][nf], a_frag) ->
// lane(r,g) holds out[b=r+16*hf][l][nbase+nf*16+g*4 .. +3] -> 16-B dwordx4
// stores, 8 per wave.
// mfma_f32_16x16x32_bf16: A-op row=lane&15, k=(lane>>4)*8+j; B-op col=lane&15;
// C/D col=lane&15, row=(lane>>4)*4+reg.
__global__ __launch_bounds__(256) void vaw_single_kernel(
        const float* __restrict__ A, const short* __restrict__ Wt,
        float* __restrict__ out) {
    __shared__ __align__(16) float aLds[B_ * E_];   // 32 KB

    const int l    = blockIdx.x;
    const int s    = l % MAXSTEP;
    const int wv   = threadIdx.x >> 6;
    const int lane = threadIdx.x & 63;
    const int r    = lane & 15;
    const int g    = lane >> 4;
    const int nbase = wv * 64;
    const int key   = r & 7;                 // (r+16)&7 == r&7

    // ---- Stage first (oldest vmcnt entries): wave wv stages rows t*4+wv.
#pragma unroll
    for (int t = 0; t < 8; ++t) {
        const int b  = t * 4 + wv;
        const int cg = lane ^ (b & 7);
        const float* gp = A + ((size_t)b * L_ + l) * E_ + cg * 4;
        __builtin_amdgcn_global_load_lds(
            (const __attribute__((address_space(1))) void*)gp,
            (__attribute__((address_space(3))) void*)&aLds[b * 256],
            16, 0, 0);
    }
    __builtin_amdgcn_sched_barrier(0);

    // ---- breg second: 32 x 16B loads (L2/L3-resident Wt).
    const short* wtb = Wt + ((size_t)s * H_ + nbase + r) * E_ + g * 8;
    bf16x8 breg[8][4];
#pragma unroll
    for (int kk = 0; kk < 8; ++kk)
#pragma unroll
        for (int nf = 0; nf < 4; ++nf)
            breg[kk][nf] = *(const bf16x8*)(wtb + (size_t)nf * 16 * E_ + kk * 32);
    __builtin_amdgcn_sched_barrier(0);

    asm volatile("s_waitcnt vmcnt(32)" ::: "memory");   // stage landed
    __builtin_amdgcn_s_barrier();
    __builtin_amdgcn_sched_barrier(0);

    // acc[nf][hf]: nf = h-frag, hf = b-half (0: b=r, 1: b=r+16)
    f32x4 acc[4][2];
#pragma unroll
    for (int nf = 0; nf < 4; ++nf)
#pragma unroll
        for (int hf = 0; hf < 2; ++hf)
            acc[nf][hf] = f32x4{0.f, 0.f, 0.f, 0.f};

#pragma unroll
    for (int kk = 0; kk < 8; ++kk) {
        const int c0 = kk * 8 + g * 2;
        f32x4 a0lo = *(const f32x4*)&aLds[r * 256 + ((c0 ^ key) << 2)];
        f32x4 a0hi = *(const f32x4*)&aLds[r * 256 + (((c0 + 1) ^ key) << 2)];
        f32x4 a1lo = *(const f32x4*)&aLds[(r + 16) * 256 + ((c0 ^ key) << 2)];
        f32x4 a1hi = *(const f32x4*)&aLds[(r + 16) * 256 + (((c0 + 1) ^ key) << 2)];
        bf16x8 a0, a1;
#pragma unroll
        for (int j = 0; j < 4; ++j) {
            a0[j]     = cvt1(a0lo[j]);
            a0[j + 4] = cvt1(a0hi[j]);
            a1[j]     = cvt1(a1lo[j]);
            a1[j + 4] = cvt1(a1hi[j]);
        }
#pragma unroll
        for (int nf = 0; nf < 4; ++nf) {
            acc[nf][0] = __builtin_amdgcn_mfma_f32_16x16x32_bf16(breg[kk][nf], a0, acc[nf][0], 0, 0, 0);
            acc[nf][1] = __builtin_amdgcn_mfma_f32_16x16x32_bf16(breg[kk][nf], a1, acc[nf][1], 0, 0, 0);
        }
    }

    // Coalesced epilogue: one dwordx4 per (hf, nf) = 8 stores/wave.
#pragma unroll
    for (int hf = 0; hf < 2; ++hf) {
        const int b = r + 16 * hf;
        float* orow = out + ((size_t)b * L_ + l) * H_ + nbase + g * 4;
#pragma unroll
        for (int nf = 0; nf < 4; ++nf)
            *(f32x4*)(orow + nf * 16) = acc[nf][hf];
    }
    if (l == L_ - 1) {
        float* out2 = out + (size_t)B_ * L_ * H_;
#pragma unroll
        for (int hf = 0; hf < 2; ++hf) {
            const int b = r + 16 * hf;
            float* orow = out2 + (size_t)b * H_ + nbase + g * 4;
#pragma unroll
            for (int nf = 0; nf < 4; ++nf)
                *(f32x4*)(orow + nf * 16) = acc[nf][hf];
        }
    }
}

// Fallback (no workspace): fp32 B loads per k-step, single-shot structure.
__global__ __launch_bounds__(256) void vaw_fallback_kernel(
        const float* __restrict__ A, const float* __restrict__ W, float* __restrict__ out) {
    __shared__ __align__(16) float aLds[B_ * E_];
    const int l    = blockIdx.x;
    const int sidx = l % MAXSTEP;
    const int wv   = threadIdx.x >> 6;
    const int lane = threadIdx.x & 63;
    const int r    = lane & 15;
    const int g    = lane >> 4;
    const int nbase = wv * 64;
    const int key   = r & 7;

#pragma unroll
    for (int t = 0; t < 8; ++t) {
        const int b  = t * 4 + wv;
        const int cg = lane ^ (b & 7);
        const float* gp = A + ((size_t)b * L_ + l) * E_ + cg * 4;
        __builtin_amdgcn_global_load_lds(
            (const __attribute__((address_space(1))) void*)gp,
            (__attribute__((address_space(3))) void*)&aLds[b * 256],
            16, 0, 0);
    }
    asm volatile("s_waitcnt vmcnt(0)" ::: "memory");
    __builtin_amdgcn_s_barrier();
    __builtin_amdgcn_sched_barrier(0);

    f32x4 acc[2][4] = {};
    const float* Wf = W + (size_t)sidx * E_ * H_;
#pragma unroll 2
    for (int kk = 0; kk < 8; ++kk) {
        const int k0 = kk * 32;
        const int c0 = kk * 8 + g * 2;
        f32x4 a0lo = *(const f32x4*)&aLds[r * 256 + ((c0 ^ key) << 2)];
        f32x4 a0hi = *(const f32x4*)&aLds[r * 256 + (((c0 + 1) ^ key) << 2)];
        f32x4 a1lo = *(const f32x4*)&aLds[(r + 16) * 256 + ((c0 ^ key) << 2)];
        f32x4 a1hi = *(const f32x4*)&aLds[(r + 16) * 256 + (((c0 + 1) ^ key) << 2)];
        bf16x8 a0, a1;
#pragma unroll
        for (int j = 0; j < 4; ++j) {
            a0[j]     = cvt1(a0lo[j]);
            a0[j + 4] = cvt1(a0hi[j]);
            a1[j]     = cvt1(a1lo[j]);
            a1[j + 4] = cvt1(a1hi[j]);
        }
        bf16x8 b0, b1, b2, b3;
#pragma unroll
        for (int j = 0; j < 8; ++j) {
            const size_t krow = (size_t)(k0 + g * 8 + j) * H_;
            b0[j] = cvt1(Wf[krow + nbase +  0 + r]);
            b1[j] = cvt1(Wf[krow + nbase + 16 + r]);
            b2[j] = cvt1(Wf[krow + nbase + 32 + r]);
            b3[j] = cvt1(Wf[krow + nbase + 48 + r]);
        }
        acc[0][0] = __builtin_amdgcn_mfma_f32_16x16x32_bf16(a0, b0, acc[0][0], 0, 0, 0);
        acc[0][1] = __builtin_amdgcn_mfma_f32_16x16x32_bf16(a0, b1, acc[0][1], 0, 0, 0);
        acc[0][2] = __builtin_amdgcn_mfma_f32_16x16x32_bf16(a0, b2, acc[0][2], 0, 0, 0);
        acc[0][3] = __builtin_amdgcn_mfma_f32_16x16x32_bf16(a0, b3, acc[0][3], 0, 0, 0);
        acc[1][0] = __builtin_amdgcn_mfma_f32_16x16x32_bf16(a1, b0, acc[1][0], 0, 0, 0);
        acc[1][1] = __builtin_amdgcn_mfma_f32_16x16x32_bf16(a1, b1, acc[1][1], 0, 0, 0);
        acc[1][2] = __builtin_amdgcn_mfma_f32_16x16x32_bf16(a1, b2, acc[1][2], 0, 0, 0);
        acc[1][3] = __builtin_amdgcn_mfma_f32_16x16x32_bf16(a1, b3, acc[1][3], 0, 0, 0);
    }

    const int row0 = g * 4;
#pragma unroll
    for (int mf = 0; mf < 2; ++mf)
#pragma unroll
        for (int nf = 0; nf < 4; ++nf) {
            const int h = nbase + nf * 16 + r;
#pragma unroll
            for (int i = 0; i < 4; ++i) {
                const int bb = mf * 16 + row0 + i;
                out[((size_t)bb * L_ + l) * H_ + h] = acc[mf][nf][i];
            }
        }
    if (l == L_ - 1) {
        float* out2 = out + (size_t)B_ * L_ * H_;
#pragma unroll
        for (int mf = 0; mf < 2; ++mf)
#pragma unroll
            for (int nf = 0; nf < 4; ++nf) {
                const int h = nbase + nf * 16 + r;
#pragma unroll
                for (int i = 0; i < 4; ++i) {
                    const int bb = mf * 16 + row0 + i;
                    out2[(size_t)bb * H_ + h] = acc[mf][nf][i];
                }
            }
    }
}

extern "C" void kernel_launch(void* const* d_in, const int* in_sizes, int n_in,
                              void* d_out, int out_size, void* d_ws, size_t ws_size,
                              hipStream_t stream) {
    const float* word_rep = (const float*)d_in[0];
    const float* cnn      = (const float*)d_in[1];
    float* out = (float*)d_out;

    const size_t wt_bytes = (size_t)MAXSTEP * E_ * H_ * sizeof(short);   // 2.62 MB
    if (ws_size >= wt_bytes) {
        short* wt = (short*)d_ws;
        transpose_w_kernel<<<dim3(8, 8, 20), dim3(32, 8), 0, stream>>>(cnn, wt);
        vaw_single_kernel<<<dim3(L_), dim3(256), 0, stream>>>(word_rep, wt, out);
    } else {
        vaw_fallback_kernel<<<dim3(L_), dim3(256), 0, stream>>>(word_rep, cnn, out);
    }
}